// Round 2
// baseline (646.354 us; speedup 1.0000x reference)
//
#include <hip/hip_runtime.h>
#include <hip/hip_bf16.h>
#include <math.h>

#define B_   1024
#define N_   200
#define NR_  208      // padded rows (13 x 16)
#define NT_  13
#define E_   256
#define R_   256
#define K6_  1536

typedef __attribute__((ext_vector_type(8))) short bf16x8;
typedef __attribute__((ext_vector_type(4))) float f32x4;

__device__ __forceinline__ unsigned short f2bf(float f) {
  unsigned int u = __float_as_uint(f);
  u += 0x7fffu + ((u >> 16) & 1u);          // RNE
  return (unsigned short)(u >> 16);
}

// HW packed cvt (v_cvt_pk_bf16_f32), RNE — bit-identical to f2bf for finite vals
__device__ __forceinline__ unsigned int pk_bf(float lo, float hi) {
  float2 t; t.x = lo; t.y = hi;
  __hip_bfloat162 h = __float22bfloat162_rn(t);
  unsigned int u;
  __builtin_memcpy(&u, &h, 4);
  return u;
}

__device__ __forceinline__ float gelu_exact(float x) {
  return 0.5f * x * (1.f + erff(x * 0.70710678118654752f));
}

// ---------------- cast rel_w and sp_w to bf16 in ws ----------------
__global__ __launch_bounds__(256) void k_cast(const float* __restrict__ rel_w,
                                              const float* __restrict__ sp_w,
                                              unsigned short* __restrict__ rw_bf,
                                              unsigned short* __restrict__ spw_bf) {
  int idx = blockIdx.x * 256 + threadIdx.x;
  if (idx < E_ * R_) rw_bf[idx] = f2bf(rel_w[idx]);
  int j = idx - E_ * R_;
  if (j >= 0 && j < 3 * E_ * K6_) spw_bf[j] = f2bf(sp_w[j]);
}

// ------- k_prep: fused q_key -> (csq logits, wts) -> q_proj -> t(bf16) -------
__global__ __launch_bounds__(256) void k_prep(
    const float* __restrict__ r_emb, const float* __restrict__ rel_w,
    const float* __restrict__ csq_w, const float* __restrict__ csq_b,
    const float* __restrict__ csl_w, const float* __restrict__ csl_b,
    const float* __restrict__ attn_w,
    unsigned short* __restrict__ t_bf, float* __restrict__ wts) {
  __shared__ __align__(16) float re[4][256];
  __shared__ __align__(16) float qk[4][256];
  __shared__ __align__(16) float sqs[4][256];
  __shared__ __align__(16) float qp[3][4][256];
  __shared__ float lg[4][3];
  int b0 = blockIdx.x * 4;
  int tid = threadIdx.x;
  int e = tid;
#pragma unroll
  for (int i = 0; i < 4; ++i)
    re[i][tid] = r_emb[(size_t)(b0 + i) * 256 + tid];
  __syncthreads();
  {
    float qkv[4], sv[4];
#pragma unroll
    for (int i = 0; i < 4; ++i) { qkv[i] = 0.f; sv[i] = 0.f; }
    const float4* w4 = (const float4*)(rel_w) + (size_t)e * 64;
    const float4* c4 = (const float4*)(csq_w) + (size_t)e * 64;
    for (int r = 0; r < 64; ++r) {
      float4 w = w4[r];
      float4 c = c4[r];
#pragma unroll
      for (int i = 0; i < 4; ++i) {
        float4 x = ((const float4*)re[i])[r];
        qkv[i] += w.x * x.x + w.y * x.y + w.z * x.z + w.w * x.w;
        sv[i] += c.x * x.x + c.y * x.y + c.z * x.z + c.w * x.w;
      }
    }
    float cb = csq_b[e];
#pragma unroll
    for (int i = 0; i < 4; ++i) {
      qk[i][e] = qkv[i];
      sqs[i][e] = sv[i] + cb;
    }
  }
  __syncthreads();
  if (tid < 12) {
    int i = tid / 3, k = tid % 3;
    float acc = csl_b[k];
    for (int ee = 0; ee < 256; ++ee) acc += sqs[i][ee] * csl_w[k * 256 + ee];
    lg[i][k] = acc;
  }
  __syncthreads();
  if (tid < 4) {
    float l0 = lg[tid][0], l1 = lg[tid][1], l2 = lg[tid][2];
    float m = fmaxf(l0, fmaxf(l1, l2));
    float e0 = expf(l0 - m), e1 = expf(l1 - m), e2 = expf(l2 - m);
    float inv = 1.f / (e0 + e1 + e2);
    wts[(b0 + tid) * 4 + 0] = e0 * inv;
    wts[(b0 + tid) * 4 + 1] = e1 * inv;
    wts[(b0 + tid) * 4 + 2] = e2 * inv;
  }
  {
    float qpv[3][4];
#pragma unroll
    for (int s = 0; s < 3; ++s)
#pragma unroll
      for (int i = 0; i < 4; ++i) qpv[s][i] = 0.f;
#pragma unroll
    for (int s = 0; s < 3; ++s) {
      const float4* a4 = (const float4*)(attn_w) + ((size_t)s * 256 + e) * 64;
      for (int r = 0; r < 64; ++r) {
        float4 w = a4[r];
#pragma unroll
        for (int i = 0; i < 4; ++i) {
          float4 x = ((const float4*)qk[i])[r];
          qpv[s][i] += w.x * x.x + w.y * x.y + w.z * x.z + w.w * x.w;
        }
      }
    }
    __syncthreads();
#pragma unroll
    for (int s = 0; s < 3; ++s)
#pragma unroll
      for (int i = 0; i < 4; ++i) qp[s][i][e] = qpv[s][i];
  }
  __syncthreads();
  {
    int r = tid;
    float tacc[3][4];
#pragma unroll
    for (int s = 0; s < 3; ++s)
#pragma unroll
      for (int i = 0; i < 4; ++i) tacc[s][i] = 0.f;
    for (int e4 = 0; e4 < 64; ++e4) {
      float4 qv[3][4];
#pragma unroll
      for (int s = 0; s < 3; ++s)
#pragma unroll
        for (int i = 0; i < 4; ++i)
          qv[s][i] = ((const float4*)qp[s][i])[e4];
#pragma unroll
      for (int j = 0; j < 4; ++j) {
        float w = rel_w[(size_t)(e4 * 4 + j) * 256 + r];
#pragma unroll
        for (int s = 0; s < 3; ++s)
#pragma unroll
          for (int i = 0; i < 4; ++i) {
            float q = (j == 0) ? qv[s][i].x : (j == 1) ? qv[s][i].y
                      : (j == 2) ? qv[s][i].z : qv[s][i].w;
            tacc[s][i] = fmaf(q, w, tacc[s][i]);
          }
      }
    }
    // t as bf16, layout [b][s][r] — consumed as MFMA B-fragments in k1
#pragma unroll
    for (int s = 0; s < 3; ++s)
#pragma unroll
      for (int i = 0; i < 4; ++i)
        t_bf[((size_t)(b0 + i) * 3 + s) * 256 + r] = f2bf(tacc[s][i]);
  }
}

// ------------- K1: fused msgs-GEMM + PNA stats + attention -------------------
// 1024 threads (16 waves), block = one b. 7-slot tile buffer (74 KB LDS) with
// in-place restaging -> 2 blocks/CU (32 waves). H1 = tiles 0..6, H2 = 7..12.
__global__ __launch_bounds__(1024, 8) void k1_main(
    const float* __restrict__ nb_rel, const float* __restrict__ delta_t,
    const unsigned char* __restrict__ hm_raw, const float* __restrict__ e_emb,
    const float* __restrict__ p_lt1, const float* __restrict__ p_lt2,
    const float* __restrict__ p_sh, const float* __restrict__ p_lgm,
    const unsigned short* __restrict__ rw_bf, const unsigned short* __restrict__ t_bf,
    unsigned short* __restrict__ feats) {
  __shared__ __align__(16) struct {
    unsigned int a[7 * 16 * 132];  // 7 tile slots, row stride 264 bf16 (256+8 pad)
    float c[3][NR_];               // unmasked per-scale decay*window weights
    float p[3][NR_];               // logits -> exp scratch
    float nmeta[NR_ * 12];         // [0..2]=mf*c [3]=off(0|1e4) [4..6]=q [7]=mf
  } sm;
  int b = blockIdx.x;
  int tid = threadIdx.x;
  int lane = tid & 63, wave = tid >> 6;
  int row16 = lane & 15, quad = lane >> 4;

  // ---- mask dtype detection: probe first 1024 bytes ----
  int hasNZoff = 0, hasFP = 0;
  {
    unsigned char cc = hm_raw[tid];
    if ((tid & 3) != 0 && cc != 0) {
      hasNZoff = 1;
      if (cc == 0x3Fu || cc == 0x80u) hasFP = 1;
    }
  }
  int cntNZ = __syncthreads_count(hasNZoff);
  int cntFP = __syncthreads_count(hasFP);
  int mmode = (cntNZ == 0) ? 0 : (cntFP > 0 ? 2 : 1);  // 0=int32 1=bool 2=f32

  float tau1 = __expf(p_lt1[0]);
  float tau2 = __expf(p_lt2[0]) + tau1;
  float sharp = fminf(fmaxf(p_sh[0], 0.1f), 5.0f);
  float gamma = __expf(p_lgm[0]);

  bool mk = false;
  if (tid < NR_) {
    float mf = 0.f, c0 = 0.f, c1 = 0.f, c2 = 0.f;
    if (tid < N_) {
      size_t mi = (size_t)b * N_ + tid;
      if (mmode == 0)      mk = ((const int*)hm_raw)[mi] != 0;
      else if (mmode == 1) mk = hm_raw[mi] != 0;
      else                 mk = ((const float*)hm_raw)[mi] != 0.f;
      float dt = delta_t[mi];
      mf = mk ? 1.f : 0.f;
      float decay = __expf(-gamma * fmaxf(dt, 0.f));
      float wf = 1.f / (1.f + __expf(sharp * (dt - tau1)));
      float wc = 1.f / (1.f + __expf(-sharp * (dt - tau2)));
      float wm = fmaxf(1.f - wf - wc, 0.f);
      c0 = decay * wf; c1 = decay * wm; c2 = decay * wc;
    }
    sm.c[0][tid] = c0; sm.c[1][tid] = c1; sm.c[2][tid] = c2;
    f32x4 w0, w1;
    w0[0] = mf * c0; w0[1] = mf * c1; w0[2] = mf * c2; w0[3] = mk ? 0.f : 1e4f;
    w1[0] = 0.f; w1[1] = 0.f; w1[2] = 0.f; w1[3] = mf;
    *(f32x4*)&sm.nmeta[tid * 12]     = w0;
    *(f32x4*)&sm.nmeta[tid * 12 + 4] = w1;
  }
  int cnt = __syncthreads_count(mk ? 1 : 0);
  float nvf = fmaxf((float)cnt, 1.f);
  bool allinv = (cnt == 0);

  const float* srcw = nb_rel + (size_t)b * N_ * 256 + lane * 4;

  // ---- stage H1 (tiles 0..6 -> slots 0..6), wave w stages row w, dist-2 ----
  {
    float4 xa = *(const float4*)(srcw + (size_t)(wave) * 256);        // tile0
    float4 xb = *(const float4*)(srcw + (size_t)(16 + wave) * 256);   // tile1
#pragma unroll
    for (int j = 0; j < 7; ++j) {
      uint2 pk;
      pk.x = pk_bf(xa.x, xa.y);
      pk.y = pk_bf(xa.z, xa.w);
      *(uint2*)&sm.a[(j * 16 + wave) * 132 + lane * 2] = pk;
      xa = xb;
      if (j + 2 < 7)
        xb = *(const float4*)(srcw + (size_t)((j + 2) * 16 + wave) * 256);  // rows <=111
    }
  }
  __syncthreads();

  // ---- logits H1 (waves 0..6; slot==tile==wave) + e_emb copy (wave 13) ----
  if (wave < 7) {
    bf16x8 tfrag[8];
    {
      int sr = (row16 < 3) ? row16 : 0;
      const unsigned short* tb = t_bf + ((size_t)b * 3 + sr) * 256 + quad * 8;
      bf16x8 zer = {0, 0, 0, 0, 0, 0, 0, 0};
#pragma unroll
      for (int ks = 0; ks < 8; ++ks) {
        bf16x8 tv = *(const bf16x8*)(tb + ks * 32);
        tfrag[ks] = (row16 < 3) ? tv : zer;
      }
    }
    f32x4 acc;
#pragma unroll
    for (int cc = 0; cc < 4; ++cc) acc[cc] = 0.f;
#pragma unroll
    for (int ks = 0; ks < 8; ++ks) {
      bf16x8 af = *(const bf16x8*)&sm.a[(wave * 16 + row16) * 132 + ks * 16 + quad * 4];
      acc = __builtin_amdgcn_mfma_f32_16x16x32_bf16(af, tfrag[ks], acc, 0, 0, 0);
    }
    if (row16 < 3) {
#pragma unroll
      for (int rg = 0; rg < 4; ++rg) {
        int n = wave * 16 + quad * 4 + rg;   // 0..111
        float cw = sm.c[row16][n];
        float mf = sm.nmeta[n * 12 + 7];
        float l = cw * acc[rg] * 0.0625f;
        l = (mf > 0.5f) ? l : -1e4f;
        if (allinv) l = (n < N_) ? 0.f : -1e4f;
        sm.p[row16][n] = l;
      }
    }
  } else if (wave == 13) {
    for (int i = lane; i < 256; i += 64) {
      unsigned short v = f2bf(e_emb[(size_t)b * 256 + i]);
      feats[((size_t)0 * B_ + b) * K6_ + 1280 + i] = v;
      feats[((size_t)1 * B_ + b) * K6_ + 1280 + i] = v;
      feats[((size_t)2 * B_ + b) * K6_ + 1280 + i] = v;
    }
  }
  __syncthreads();

  // ---- stage H2 (tiles 7..12 -> slots 0..5), dist-2; rows >=200 clamped ----
  {
    float4 xa = *(const float4*)(srcw + (size_t)(112 + wave) * 256);  // tile7
    float4 xb = *(const float4*)(srcw + (size_t)(128 + wave) * 256);  // tile8
#pragma unroll
    for (int j = 0; j < 6; ++j) {
      uint2 pk;
      pk.x = pk_bf(xa.x, xa.y);
      pk.y = pk_bf(xa.z, xa.w);
      *(uint2*)&sm.a[(j * 16 + wave) * 132 + lane * 2] = pk;
      xa = xb;
      if (j + 2 < 6) {
        int n = 112 + (j + 2) * 16 + wave;
        int gn = (n < N_) ? n : (N_ - 1);
        xb = *(const float4*)(srcw + (size_t)gn * 256);
      }
    }
  }
  __syncthreads();

  // ---- logits H2 (waves 7..12; slot = wave-7, tile = wave) ----
  if (wave >= 7 && wave < 13) {
    bf16x8 tfrag[8];
    {
      int sr = (row16 < 3) ? row16 : 0;
      const unsigned short* tb = t_bf + ((size_t)b * 3 + sr) * 256 + quad * 8;
      bf16x8 zer = {0, 0, 0, 0, 0, 0, 0, 0};
#pragma unroll
      for (int ks = 0; ks < 8; ++ks) {
        bf16x8 tv = *(const bf16x8*)(tb + ks * 32);
        tfrag[ks] = (row16 < 3) ? tv : zer;
      }
    }
    f32x4 acc;
#pragma unroll
    for (int cc = 0; cc < 4; ++cc) acc[cc] = 0.f;
    int slot = wave - 7;
#pragma unroll
    for (int ks = 0; ks < 8; ++ks) {
      bf16x8 af = *(const bf16x8*)&sm.a[(slot * 16 + row16) * 132 + ks * 16 + quad * 4];
      acc = __builtin_amdgcn_mfma_f32_16x16x32_bf16(af, tfrag[ks], acc, 0, 0, 0);
    }
    if (row16 < 3) {
#pragma unroll
      for (int rg = 0; rg < 4; ++rg) {
        int n = wave * 16 + quad * 4 + rg;   // 112..207
        float cw = sm.c[row16][n];
        float mf = sm.nmeta[n * 12 + 7];
        float l = cw * acc[rg] * 0.0625f;
        l = (mf > 0.5f) ? l : -1e4f;
        if (allinv) l = (n < N_) ? 0.f : -1e4f;
        sm.p[row16][n] = l;
      }
    }
  }

  // B-fragment preload (wave owns 16 e-cols) — in flight across softmax phase
  bf16x8 bfr[8];
  {
    int e = wave * 16 + row16;
#pragma unroll
    for (int ks = 0; ks < 8; ++ks)
      bfr[ks] = *(const bf16x8*)(rw_bf + (size_t)e * 256 + ks * 32 + quad * 8);
  }
  __syncthreads();

  // ---- softmax (waves 0-2): max -> exp(store back) -> normalize into q ----
  if (wave < 3) {
    int s = wave;
    float m = -1e30f;
    for (int n = lane; n < NR_; n += 64) m = fmaxf(m, sm.p[s][n]);
#pragma unroll
    for (int o = 32; o >= 1; o >>= 1) m = fmaxf(m, __shfl_xor(m, o, 64));
    float ssum = 0.f;
    for (int n = lane; n < NR_; n += 64) {
      float ev = __expf(sm.p[s][n] - m);
      sm.p[s][n] = ev;
      ssum += ev;
    }
#pragma unroll
    for (int o = 32; o >= 1; o >>= 1) ssum += __shfl_xor(ssum, o, 64);
    float inv = 1.f / ssum;
    for (int n = lane; n < NR_; n += 64)
      sm.nmeta[n * 12 + 4 + s] = sm.p[s][n] * inv * sm.c[s][n];
  }
  __syncthreads();

  // ---- MFMA GEMM + register stats; pass 1 = H2 (slots 0..5, tiles 7..12)
  //      with rolling restage of H1 tiles 0..5; pass 2 = H1 (slots 0..6) ----
  float s_mean[3], s_mx[3], s_mn[3], s_sq[3], s_av[3];
#pragma unroll
  for (int s = 0; s < 3; ++s) {
    s_mean[s] = 0.f; s_mx[s] = -1e30f; s_mn[s] = 1e30f;
    s_sq[s] = 0.f; s_av[s] = 0.f;
  }

#define GEMM_TILE(SLOT, NTR) do {                                              \
    f32x4 acc;                                                                 \
    acc[0] = 0.f; acc[1] = 0.f; acc[2] = 0.f; acc[3] = 0.f;                    \
    _Pragma("unroll")                                                          \
    for (int ks = 0; ks < 8; ++ks) {                                           \
      bf16x8 af = *(const bf16x8*)&sm.a[((SLOT) * 16 + row16) * 132 + ks * 16 + quad * 4]; \
      acc = __builtin_amdgcn_mfma_f32_16x16x32_bf16(af, bfr[ks], acc, 0, 0, 0);\
    }                                                                          \
    int nb = (NTR) * 16 + quad * 4;                                            \
    _Pragma("unroll")                                                          \
    for (int rg = 0; rg < 4; ++rg) {                                           \
      const float* nm = &sm.nmeta[(size_t)(nb + rg) * 12];                     \
      f32x4 w0 = *(const f32x4*)nm;                                            \
      f32x4 w1 = *(const f32x4*)(nm + 4);                                      \
      float m = acc[rg];                                                       \
      _Pragma("unroll")                                                        \
      for (int s = 0; s < 3; ++s) {                                            \
        float vm = w0[s] * m;                                                  \
        s_mean[s] += vm;                                                       \
        s_mx[s] = fmaxf(s_mx[s], vm);                                          \
        s_mn[s] = fminf(s_mn[s], fmaf(w0[s], m, w0[3]));                       \
        float cv = fminf(fmaxf(vm, -10.f), 10.f);                              \
        s_sq[s] = fmaf(cv, cv, s_sq[s]);                                       \
        s_av[s] = fmaf(w1[s], m, s_av[s]);                                     \
      }                                                                        \
    }                                                                          \
  } while (0)

  {
    float4 xa = *(const float4*)(srcw + (size_t)(wave) * 256);  // H1 tile0 row w
    for (int j = 0; j < 6; ++j) {
      GEMM_TILE(j, 7 + j);
      __syncthreads();   // all waves done reading slot j (H2) -> safe to rewrite
      uint2 pk;
      pk.x = pk_bf(xa.x, xa.y);
      pk.y = pk_bf(xa.z, xa.w);
      *(uint2*)&sm.a[(j * 16 + wave) * 132 + lane * 2] = pk;
      if (j < 5)
        xa = *(const float4*)(srcw + (size_t)((j + 1) * 16 + wave) * 256);  // rows <=95
    }
  }
  __syncthreads();  // all restage writes precede this barrier in program order
  for (int j = 0; j < 7; ++j) {
    GEMM_TILE(j, j);
  }
#undef GEMM_TILE

  // ---- reduce across quads, write feats (bf16) ----
#pragma unroll
  for (int s = 0; s < 3; ++s) {
    float vmean = s_mean[s];
    vmean += __shfl_xor(vmean, 16, 64); vmean += __shfl_xor(vmean, 32, 64);
    float vmx = s_mx[s];
    vmx = fmaxf(vmx, __shfl_xor(vmx, 16, 64)); vmx = fmaxf(vmx, __shfl_xor(vmx, 32, 64));
    float vmn = s_mn[s];
    vmn = fminf(vmn, __shfl_xor(vmn, 16, 64)); vmn = fminf(vmn, __shfl_xor(vmn, 32, 64));
    float vsq = s_sq[s];
    vsq += __shfl_xor(vsq, 16, 64); vsq += __shfl_xor(vsq, 32, 64);
    float vav = s_av[s];
    vav += __shfl_xor(vav, 16, 64); vav += __shfl_xor(vav, 32, 64);
    if (lane < 16) {
      int e = wave * 16 + lane;
      size_t base = ((size_t)s * B_ + b) * K6_;
      float meanv = vmean / nvf;
      float stdv = sqrtf(fmaxf(vsq / nvf - meanv * meanv, 1e-6f));
      float mnv = fminf(fmaxf(vmn, -1e4f), 1e4f);
      feats[base + e] = f2bf(meanv);
      feats[base + 256 + e] = f2bf(vmx);
      feats[base + 512 + e] = f2bf(mnv);
      feats[base + 768 + e] = f2bf(stdv);
      feats[base + 1024 + e] = f2bf(vav);
    }
  }
}

// ------- K2: h = feats(bf16) @ sp_w^T + bias -> hbuf (pre-LN, fp32) -------
__global__ __launch_bounds__(256) void k2_kernel(
    const unsigned short* __restrict__ feats, const unsigned short* __restrict__ spw_bf,
    const float* __restrict__ sp_b, float* __restrict__ hbuf) {
  __shared__ __align__(16) unsigned int a[16 * 132];
  int id = blockIdx.x;
  int s = id >> 7;
  int rem = id & 127;
  int b0 = (rem >> 1) * 16;
  int e0 = (rem & 1) * 128;
  int tid = threadIdx.x, lane = tid & 63, wave = tid >> 6;
  int row16 = lane & 15, quad = lane >> 4;
  f32x4 acc[2];
#pragma unroll
  for (int t = 0; t < 2; ++t)
#pragma unroll
    for (int cc = 0; cc < 4; ++cc) acc[t][cc] = 0.f;

  for (int kc = 0; kc < 6; ++kc) {
    __syncthreads();
    for (int j = tid; j < 512; j += 256) {
      int rw = j >> 5, ck = j & 31;
      bf16x8 v = *(const bf16x8*)(feats + ((size_t)s * B_ + b0 + rw) * K6_ + kc * 256 + ck * 8);
      *(bf16x8*)((unsigned short*)&a[rw * 132] + ck * 8) = v;
    }
    __syncthreads();
#pragma unroll
    for (int ks = 0; ks < 8; ++ks) {
      bf16x8 af = *(const bf16x8*)&a[row16 * 132 + ks * 16 + quad * 4];
#pragma unroll
      for (int t = 0; t < 2; ++t) {
        int e = e0 + wave * 32 + t * 16 + row16;
        bf16x8 bfr = *(const bf16x8*)(spw_bf + ((size_t)s * E_ + e) * K6_ + kc * 256 + ks * 32 + quad * 8);
        acc[t] = __builtin_amdgcn_mfma_f32_16x16x32_bf16(af, bfr, acc[t], 0, 0, 0);
      }
    }
  }
#pragma unroll
  for (int t = 0; t < 2; ++t) {
    int e = e0 + wave * 32 + t * 16 + row16;
    float bias = sp_b[s * 256 + e];
#pragma unroll
    for (int rg = 0; rg < 4; ++rg) {
      int rw = quad * 4 + rg;
      hbuf[((size_t)s * B_ + b0 + rw) * 256 + e] = acc[t][rg] + bias;
    }
  }
}

// ------- K3: per b: for each s LN+gelu, weighted sum, final LN -> out -------
__global__ __launch_bounds__(256) void k3_kernel(
    const float* __restrict__ hbuf, const float* __restrict__ wts,
    const float* __restrict__ ln_g, const float* __restrict__ ln_b,
    const float* __restrict__ on_g, const float* __restrict__ on_b,
    float* __restrict__ out) {
  __shared__ float rs[4], rq[4];
  int b = blockIdx.x, tid = threadIdx.x, lane = tid & 63, wave = tid >> 6;
  float o = 0.f;
#pragma unroll
  for (int s = 0; s < 3; ++s) {
    float h = hbuf[((size_t)s * B_ + b) * 256 + tid];
    float sum = h, sq = h * h;
#pragma unroll
    for (int off = 32; off >= 1; off >>= 1) {
      sum += __shfl_xor(sum, off, 64);
      sq += __shfl_xor(sq, off, 64);
    }
    if (lane == 0) { rs[wave] = sum; rq[wave] = sq; }
    __syncthreads();
    float ts = rs[0] + rs[1] + rs[2] + rs[3];
    float tq = rq[0] + rq[1] + rq[2] + rq[3];
    __syncthreads();
    float mu = ts * (1.f / 256.f);
    float var = tq * (1.f / 256.f) - mu * mu;
    float rstd = rsqrtf(var + 1e-5f);
    float v = (h - mu) * rstd * ln_g[s * 256 + tid] + ln_b[s * 256 + tid];
    o += wts[b * 4 + s] * gelu_exact(v);
  }
  float sum = o, sq = o * o;
#pragma unroll
  for (int off = 32; off >= 1; off >>= 1) {
    sum += __shfl_xor(sum, off, 64);
    sq += __shfl_xor(sq, off, 64);
  }
  if (lane == 0) { rs[wave] = sum; rq[wave] = sq; }
  __syncthreads();
  float ts = rs[0] + rs[1] + rs[2] + rs[3];
  float tq = rq[0] + rq[1] + rq[2] + rq[3];
  float mu = ts * (1.f / 256.f);
  float var = tq * (1.f / 256.f) - mu * mu;
  float rstd = rsqrtf(var + 1e-5f);
  out[(size_t)b * 256 + tid] = (o - mu) * rstd * on_g[tid] + on_b[tid];
}

extern "C" void kernel_launch(void* const* d_in, const int* in_sizes, int n_in,
                              void* d_out, int out_size, void* d_ws, size_t ws_size,
                              hipStream_t stream) {
  const float* e_emb   = (const float*)d_in[0];
  const float* nb_rel  = (const float*)d_in[1];
  const float* delta_t = (const float*)d_in[2];
  const float* r_emb   = (const float*)d_in[3];
  const unsigned char* hist_mask = (const unsigned char*)d_in[4]; // dtype auto-detected
  const float* rel_w   = (const float*)d_in[5];
  const float* lt1     = (const float*)d_in[6];
  const float* lt2     = (const float*)d_in[7];
  const float* shp     = (const float*)d_in[8];
  const float* lgm     = (const float*)d_in[9];
  const float* attn_w  = (const float*)d_in[10];
  const float* sp_w    = (const float*)d_in[11];
  const float* sp_b    = (const float*)d_in[12];
  const float* ln_g    = (const float*)d_in[13];
  const float* ln_b    = (const float*)d_in[14];
  const float* csq_w   = (const float*)d_in[15];
  const float* csq_b   = (const float*)d_in[16];
  const float* csl_w   = (const float*)d_in[17];
  const float* csl_b   = (const float*)d_in[18];
  const float* on_g    = (const float*)d_in[19];
  const float* on_b    = (const float*)d_in[20];
  float* out = (float*)d_out;

  char* ws = (char*)d_ws;
  unsigned short* rw_bf  = (unsigned short*)(ws + 0);         // 131072 B
  unsigned short* spw_bf = (unsigned short*)(ws + 131072);    // 2359296 B
  unsigned short* t_bf   = (unsigned short*)(ws + 2490368);   // 1572864 B
  float* wts    = (float*)(ws + 4063232);                     // 16 KB
  unsigned short* feats = (unsigned short*)(ws + 4079616);    // 9437184 B
  float* hbuf   = (float*)(ws + 13516800);                    // 3 MB (total ~16.7 MB)

  hipLaunchKernelGGL(k_cast, dim3(4864), dim3(256), 0, stream, rel_w, sp_w, rw_bf, spw_bf);
  hipLaunchKernelGGL(k_prep, dim3(256), dim3(256), 0, stream, r_emb, rel_w, csq_w, csq_b,
                     csl_w, csl_b, attn_w, t_bf, wts);
  hipLaunchKernelGGL(k1_main, dim3(1024), dim3(1024), 0, stream, nb_rel, delta_t, hist_mask,
                     e_emb, lt1, lt2, shp, lgm, rw_bf, t_bf, feats);
  hipLaunchKernelGGL(k2_kernel, dim3(384), dim3(256), 0, stream, feats, spw_bf, sp_b, hbuf);
  hipLaunchKernelGGL(k3_kernel, dim3(1024), dim3(256), 0, stream, hbuf, wts, ln_g, ln_b,
                     on_g, on_b, out);
}

// Round 3
// 542.700 us; speedup vs baseline: 1.1910x; 1.1910x over previous
//
#include <hip/hip_runtime.h>
#include <hip/hip_bf16.h>
#include <math.h>

#define B_   1024
#define N_   200
#define NR_  208      // padded rows (13 x 16)
#define NT_  13
#define E_   256
#define R_   256
#define K6_  1536

typedef __attribute__((ext_vector_type(8))) short bf16x8;
typedef __attribute__((ext_vector_type(4))) float f32x4;

__device__ __forceinline__ unsigned short f2bf(float f) {
  unsigned int u = __float_as_uint(f);
  u += 0x7fffu + ((u >> 16) & 1u);          // RNE
  return (unsigned short)(u >> 16);
}

// HW packed cvt (v_cvt_pk_bf16_f32), RNE — bit-identical to f2bf for finite vals
__device__ __forceinline__ unsigned int pk_bf(float lo, float hi) {
  float2 t; t.x = lo; t.y = hi;
  __hip_bfloat162 h = __float22bfloat162_rn(t);
  unsigned int u;
  __builtin_memcpy(&u, &h, 4);
  return u;
}

__device__ __forceinline__ float gelu_exact(float x) {
  return 0.5f * x * (1.f + erff(x * 0.70710678118654752f));
}

// ---------------- cast rel_w and sp_w to bf16 in ws ----------------
__global__ __launch_bounds__(256) void k_cast(const float* __restrict__ rel_w,
                                              const float* __restrict__ sp_w,
                                              unsigned short* __restrict__ rw_bf,
                                              unsigned short* __restrict__ spw_bf) {
  int idx = blockIdx.x * 256 + threadIdx.x;
  if (idx < E_ * R_) rw_bf[idx] = f2bf(rel_w[idx]);
  int j = idx - E_ * R_;
  if (j >= 0 && j < 3 * E_ * K6_) spw_bf[j] = f2bf(sp_w[j]);
}

// ------- k_prep: fused q_key -> (csq logits, wts) -> q_proj -> t(bf16) -------
__global__ __launch_bounds__(256) void k_prep(
    const float* __restrict__ r_emb, const float* __restrict__ rel_w,
    const float* __restrict__ csq_w, const float* __restrict__ csq_b,
    const float* __restrict__ csl_w, const float* __restrict__ csl_b,
    const float* __restrict__ attn_w,
    unsigned short* __restrict__ t_bf, float* __restrict__ wts) {
  __shared__ __align__(16) float re[4][256];
  __shared__ __align__(16) float qk[4][256];
  __shared__ __align__(16) float sqs[4][256];
  __shared__ __align__(16) float qp[3][4][256];
  __shared__ float lg[4][3];
  int b0 = blockIdx.x * 4;
  int tid = threadIdx.x;
  int e = tid;
#pragma unroll
  for (int i = 0; i < 4; ++i)
    re[i][tid] = r_emb[(size_t)(b0 + i) * 256 + tid];
  __syncthreads();
  {
    float qkv[4], sv[4];
#pragma unroll
    for (int i = 0; i < 4; ++i) { qkv[i] = 0.f; sv[i] = 0.f; }
    const float4* w4 = (const float4*)(rel_w) + (size_t)e * 64;
    const float4* c4 = (const float4*)(csq_w) + (size_t)e * 64;
    for (int r = 0; r < 64; ++r) {
      float4 w = w4[r];
      float4 c = c4[r];
#pragma unroll
      for (int i = 0; i < 4; ++i) {
        float4 x = ((const float4*)re[i])[r];
        qkv[i] += w.x * x.x + w.y * x.y + w.z * x.z + w.w * x.w;
        sv[i] += c.x * x.x + c.y * x.y + c.z * x.z + c.w * x.w;
      }
    }
    float cb = csq_b[e];
#pragma unroll
    for (int i = 0; i < 4; ++i) {
      qk[i][e] = qkv[i];
      sqs[i][e] = sv[i] + cb;
    }
  }
  __syncthreads();
  if (tid < 12) {
    int i = tid / 3, k = tid % 3;
    float acc = csl_b[k];
    for (int ee = 0; ee < 256; ++ee) acc += sqs[i][ee] * csl_w[k * 256 + ee];
    lg[i][k] = acc;
  }
  __syncthreads();
  if (tid < 4) {
    float l0 = lg[tid][0], l1 = lg[tid][1], l2 = lg[tid][2];
    float m = fmaxf(l0, fmaxf(l1, l2));
    float e0 = expf(l0 - m), e1 = expf(l1 - m), e2 = expf(l2 - m);
    float inv = 1.f / (e0 + e1 + e2);
    wts[(b0 + tid) * 4 + 0] = e0 * inv;
    wts[(b0 + tid) * 4 + 1] = e1 * inv;
    wts[(b0 + tid) * 4 + 2] = e2 * inv;
  }
  {
    float qpv[3][4];
#pragma unroll
    for (int s = 0; s < 3; ++s)
#pragma unroll
      for (int i = 0; i < 4; ++i) qpv[s][i] = 0.f;
#pragma unroll
    for (int s = 0; s < 3; ++s) {
      const float4* a4 = (const float4*)(attn_w) + ((size_t)s * 256 + e) * 64;
      for (int r = 0; r < 64; ++r) {
        float4 w = a4[r];
#pragma unroll
        for (int i = 0; i < 4; ++i) {
          float4 x = ((const float4*)qk[i])[r];
          qpv[s][i] += w.x * x.x + w.y * x.y + w.z * x.z + w.w * x.w;
        }
      }
    }
    __syncthreads();
#pragma unroll
    for (int s = 0; s < 3; ++s)
#pragma unroll
      for (int i = 0; i < 4; ++i) qp[s][i][e] = qpv[s][i];
  }
  __syncthreads();
  {
    int r = tid;
    float tacc[3][4];
#pragma unroll
    for (int s = 0; s < 3; ++s)
#pragma unroll
      for (int i = 0; i < 4; ++i) tacc[s][i] = 0.f;
    for (int e4 = 0; e4 < 64; ++e4) {
      float4 qv[3][4];
#pragma unroll
      for (int s = 0; s < 3; ++s)
#pragma unroll
        for (int i = 0; i < 4; ++i)
          qv[s][i] = ((const float4*)qp[s][i])[e4];
#pragma unroll
      for (int j = 0; j < 4; ++j) {
        float w = rel_w[(size_t)(e4 * 4 + j) * 256 + r];
#pragma unroll
        for (int s = 0; s < 3; ++s)
#pragma unroll
          for (int i = 0; i < 4; ++i) {
            float q = (j == 0) ? qv[s][i].x : (j == 1) ? qv[s][i].y
                      : (j == 2) ? qv[s][i].z : qv[s][i].w;
            tacc[s][i] = fmaf(q, w, tacc[s][i]);
          }
      }
    }
    // t as bf16, layout [b][s][r] — consumed as MFMA B-fragments in k1
#pragma unroll
    for (int s = 0; s < 3; ++s)
#pragma unroll
      for (int i = 0; i < 4; ++i)
        t_bf[((size_t)(b0 + i) * 3 + s) * 256 + r] = f2bf(tacc[s][i]);
  }
}

// ------------- K1: fused msgs-GEMM + PNA stats + attention -------------------
// 1024 threads (16 waves), block = one b. STREAMING two-pass design:
// 2-slot double-buffered A tile (16.9 KB) -> total LDS ~31 KB -> 2 blocks/CU
// provided VGPR <= 64. Pass 1 = logits (tfrag live), pass 2 = stats GEMM
// (bfr+stats live) — disjoint register lifetimes keep the peak ~60.
// Pass-2 re-reads nb_rel ~2 us after pass 1 -> L3-hit, little extra HBM.
__global__ __launch_bounds__(1024, 4) void k1_main(
    const float* __restrict__ nb_rel, const float* __restrict__ delta_t,
    const unsigned char* __restrict__ hm_raw, const float* __restrict__ e_emb,
    const float* __restrict__ p_lt1, const float* __restrict__ p_lt2,
    const float* __restrict__ p_sh, const float* __restrict__ p_lgm,
    const unsigned short* __restrict__ rw_bf, const unsigned short* __restrict__ t_bf,
    unsigned short* __restrict__ feats) {
  __shared__ __align__(16) struct {
    unsigned int a[2 * 16 * 132];  // 2 slots x 16 rows, row stride 264 bf16 (256+8 pad)
    float c[3][NR_];               // unmasked per-scale decay*window weights
    float p[3][NR_];               // logits -> exp scratch
    float nmeta[NR_ * 12];         // [0..2]=mf*c [3]=off(0|1e4) [4..6]=q [7]=mf
  } sm;
  int b = blockIdx.x;
  int tid = threadIdx.x;
  int lane = tid & 63, wave = tid >> 6;
  int row16 = lane & 15, quad = lane >> 4;

  // ---- mask dtype detection: probe first 1024 bytes ----
  int hasNZoff = 0, hasFP = 0;
  {
    unsigned char cc = hm_raw[tid];
    if ((tid & 3) != 0 && cc != 0) {
      hasNZoff = 1;
      if (cc == 0x3Fu || cc == 0x80u) hasFP = 1;
    }
  }
  int cntNZ = __syncthreads_count(hasNZoff);
  int cntFP = __syncthreads_count(hasFP);
  int mmode = (cntNZ == 0) ? 0 : (cntFP > 0 ? 2 : 1);  // 0=int32 1=bool 2=f32

  float tau1 = __expf(p_lt1[0]);
  float tau2 = __expf(p_lt2[0]) + tau1;
  float sharp = fminf(fmaxf(p_sh[0], 0.1f), 5.0f);
  float gamma = __expf(p_lgm[0]);

  bool mk = false;
  if (tid < NR_) {
    float mf = 0.f, c0 = 0.f, c1 = 0.f, c2 = 0.f;
    if (tid < N_) {
      size_t mi = (size_t)b * N_ + tid;
      if (mmode == 0)      mk = ((const int*)hm_raw)[mi] != 0;
      else if (mmode == 1) mk = hm_raw[mi] != 0;
      else                 mk = ((const float*)hm_raw)[mi] != 0.f;
      float dt = delta_t[mi];
      mf = mk ? 1.f : 0.f;
      float decay = __expf(-gamma * fmaxf(dt, 0.f));
      float wf = 1.f / (1.f + __expf(sharp * (dt - tau1)));
      float wc = 1.f / (1.f + __expf(-sharp * (dt - tau2)));
      float wm = fmaxf(1.f - wf - wc, 0.f);
      c0 = decay * wf; c1 = decay * wm; c2 = decay * wc;
    }
    sm.c[0][tid] = c0; sm.c[1][tid] = c1; sm.c[2][tid] = c2;
    f32x4 w0, w1;
    w0[0] = mf * c0; w0[1] = mf * c1; w0[2] = mf * c2; w0[3] = mk ? 0.f : 1e4f;
    w1[0] = 0.f; w1[1] = 0.f; w1[2] = 0.f; w1[3] = mf;
    *(f32x4*)&sm.nmeta[tid * 12]     = w0;
    *(f32x4*)&sm.nmeta[tid * 12 + 4] = w1;
  }
  int cnt = __syncthreads_count(mk ? 1 : 0);
  float nvf = fmaxf((float)cnt, 1.f);
  bool allinv = (cnt == 0);

  const float* srcw = nb_rel + (size_t)b * N_ * 256 + lane * 4;

  // t B-fragments (pass-1 only; dead before bfr loads -> disjoint lifetime)
  bf16x8 tfrag[8];
  {
    int sr = (row16 < 3) ? row16 : 0;
    const unsigned short* tb = t_bf + ((size_t)b * 3 + sr) * 256 + quad * 8;
    bf16x8 zer = {0, 0, 0, 0, 0, 0, 0, 0};
#pragma unroll
    for (int ks = 0; ks < 8; ++ks) {
      bf16x8 tv = *(const bf16x8*)(tb + ks * 32);
      tfrag[ks] = (row16 < 3) ? tv : zer;
    }
  }

  // e_emb tail copy (wave 15) — overlapped with prologue staging
  if (wave == 15) {
    for (int i = lane; i < 256; i += 64) {
      unsigned short v = f2bf(e_emb[(size_t)b * 256 + i]);
      feats[((size_t)0 * B_ + b) * K6_ + 1280 + i] = v;
      feats[((size_t)1 * B_ + b) * K6_ + 1280 + i] = v;
      feats[((size_t)2 * B_ + b) * K6_ + 1280 + i] = v;
    }
  }

  // prologue: stage tile 0 -> slot 0 (wave w stages row w; rows 0..15 < N_)
  {
    float4 x = *(const float4*)(srcw + (size_t)wave * 256);
    uint2 pk;
    pk.x = pk_bf(x.x, x.y);
    pk.y = pk_bf(x.z, x.w);
    *(uint2*)&sm.a[wave * 132 + lane * 2] = pk;
  }
  __syncthreads();

  // ---- PASS 1: logits. Wave t computes tile t's 8 MFMAs; all waves stage t+1.
  for (int t = 0; t < NT_; ++t) {
    float4 xn;
    if (t < NT_ - 1) {
      int n = (t + 1) * 16 + wave;
      int gn = (n < N_) ? n : (N_ - 1);
      xn = *(const float4*)(srcw + (size_t)gn * 256);
    }
    if (wave == t) {
      f32x4 acc;
      acc[0] = 0.f; acc[1] = 0.f; acc[2] = 0.f; acc[3] = 0.f;
      const unsigned int* sa = &sm.a[(t & 1) * 2112];
#pragma unroll
      for (int ks = 0; ks < 8; ++ks) {
        bf16x8 af = *(const bf16x8*)&sa[row16 * 132 + ks * 16 + quad * 4];
        acc = __builtin_amdgcn_mfma_f32_16x16x32_bf16(af, tfrag[ks], acc, 0, 0, 0);
      }
      if (row16 < 3) {
#pragma unroll
        for (int rg = 0; rg < 4; ++rg) {
          int n = t * 16 + quad * 4 + rg;   // C layout: col=lane&15(=s), row=quad*4+rg
          float cw = sm.c[row16][n];
          float mf = sm.nmeta[n * 12 + 7];
          float l = cw * acc[rg] * 0.0625f;
          l = (mf > 0.5f) ? l : -1e4f;
          if (allinv) l = (n < N_) ? 0.f : -1e4f;
          sm.p[row16][n] = l;
        }
      }
    }
    if (t < NT_ - 1) {
      uint2 pk;
      pk.x = pk_bf(xn.x, xn.y);
      pk.y = pk_bf(xn.z, xn.w);
      *(uint2*)&sm.a[((t + 1) & 1) * 2112 + wave * 132 + lane * 2] = pk;
    }
    __syncthreads();
  }

  // ---- softmax (waves 0-2) ∥ bfr preload ∥ stage tile 0 -> slot 0 ----
  bf16x8 bfr[8];
  {
    int e = wave * 16 + row16;
#pragma unroll
    for (int ks = 0; ks < 8; ++ks)
      bfr[ks] = *(const bf16x8*)(rw_bf + (size_t)e * 256 + ks * 32 + quad * 8);
  }
  {
    // slot0 held tile 12, last read at t=12 before the loop's final barrier
    float4 x = *(const float4*)(srcw + (size_t)wave * 256);
    uint2 pk;
    pk.x = pk_bf(x.x, x.y);
    pk.y = pk_bf(x.z, x.w);
    *(uint2*)&sm.a[wave * 132 + lane * 2] = pk;
  }
  if (wave < 3) {
    int s = wave;
    float m = -1e30f;
    for (int n = lane; n < NR_; n += 64) m = fmaxf(m, sm.p[s][n]);
#pragma unroll
    for (int o = 32; o >= 1; o >>= 1) m = fmaxf(m, __shfl_xor(m, o, 64));
    float ssum = 0.f;
    for (int n = lane; n < NR_; n += 64) {
      float ev = __expf(sm.p[s][n] - m);
      sm.p[s][n] = ev;
      ssum += ev;
    }
#pragma unroll
    for (int o = 32; o >= 1; o >>= 1) ssum += __shfl_xor(ssum, o, 64);
    float inv = 1.f / ssum;
    for (int n = lane; n < NR_; n += 64)
      sm.nmeta[n * 12 + 4 + s] = sm.p[s][n] * inv * sm.c[s][n];
  }
  __syncthreads();

  // ---- PASS 2: stats GEMM over 13 streamed tiles (wave owns 16 e-cols) ----
  float s_mean[3], s_mx[3], s_mn[3], s_sq[3], s_av[3];
#pragma unroll
  for (int s = 0; s < 3; ++s) {
    s_mean[s] = 0.f; s_mx[s] = -1e30f; s_mn[s] = 1e30f;
    s_sq[s] = 0.f; s_av[s] = 0.f;
  }

  for (int t = 0; t < NT_; ++t) {
    float4 xn;
    if (t < NT_ - 1) {
      int n = (t + 1) * 16 + wave;
      int gn = (n < N_) ? n : (N_ - 1);
      xn = *(const float4*)(srcw + (size_t)gn * 256);
    }
    f32x4 acc;
    acc[0] = 0.f; acc[1] = 0.f; acc[2] = 0.f; acc[3] = 0.f;
    const unsigned int* sa = &sm.a[(t & 1) * 2112];
#pragma unroll
    for (int ks = 0; ks < 8; ++ks) {
      bf16x8 af = *(const bf16x8*)&sa[row16 * 132 + ks * 16 + quad * 4];
      acc = __builtin_amdgcn_mfma_f32_16x16x32_bf16(af, bfr[ks], acc, 0, 0, 0);
    }
    int nb = t * 16 + quad * 4;
#pragma unroll
    for (int rg = 0; rg < 4; ++rg) {
      const float* nm = &sm.nmeta[(size_t)(nb + rg) * 12];
      f32x4 w0 = *(const f32x4*)nm;        // cm0 cm1 cm2 off  (broadcast b128)
      f32x4 w1 = *(const f32x4*)(nm + 4);  // q0  q1  q2  mf   (broadcast b128)
      float m = acc[rg];
#pragma unroll
      for (int s = 0; s < 3; ++s) {
        float vm = w0[s] * m;
        s_mean[s] += vm;
        s_mx[s] = fmaxf(s_mx[s], vm);
        s_mn[s] = fminf(s_mn[s], fmaf(w0[s], m, w0[3]));
        float cv = fminf(fmaxf(vm, -10.f), 10.f);
        s_sq[s] = fmaf(cv, cv, s_sq[s]);
        s_av[s] = fmaf(w1[s], m, s_av[s]);
      }
    }
    if (t < NT_ - 1) {
      uint2 pk;
      pk.x = pk_bf(xn.x, xn.y);
      pk.y = pk_bf(xn.z, xn.w);
      *(uint2*)&sm.a[((t + 1) & 1) * 2112 + wave * 132 + lane * 2] = pk;
    }
    __syncthreads();
  }

  // ---- reduce across quads, write feats (bf16) ----
#pragma unroll
  for (int s = 0; s < 3; ++s) {
    float vmean = s_mean[s];
    vmean += __shfl_xor(vmean, 16, 64); vmean += __shfl_xor(vmean, 32, 64);
    float vmx = s_mx[s];
    vmx = fmaxf(vmx, __shfl_xor(vmx, 16, 64)); vmx = fmaxf(vmx, __shfl_xor(vmx, 32, 64));
    float vmn = s_mn[s];
    vmn = fminf(vmn, __shfl_xor(vmn, 16, 64)); vmn = fminf(vmn, __shfl_xor(vmn, 32, 64));
    float vsq = s_sq[s];
    vsq += __shfl_xor(vsq, 16, 64); vsq += __shfl_xor(vsq, 32, 64);
    float vav = s_av[s];
    vav += __shfl_xor(vav, 16, 64); vav += __shfl_xor(vav, 32, 64);
    if (lane < 16) {
      int e = wave * 16 + lane;
      size_t base = ((size_t)s * B_ + b) * K6_;
      float meanv = vmean / nvf;
      float stdv = sqrtf(fmaxf(vsq / nvf - meanv * meanv, 1e-6f));
      float mnv = fminf(fmaxf(vmn, -1e4f), 1e4f);
      feats[base + e] = f2bf(meanv);
      feats[base + 256 + e] = f2bf(vmx);
      feats[base + 512 + e] = f2bf(mnv);
      feats[base + 768 + e] = f2bf(stdv);
      feats[base + 1024 + e] = f2bf(vav);
    }
  }
}

// ------- K2: h = feats(bf16) @ sp_w^T + bias -> hbuf (pre-LN, fp32) -------
__global__ __launch_bounds__(256) void k2_kernel(
    const unsigned short* __restrict__ feats, const unsigned short* __restrict__ spw_bf,
    const float* __restrict__ sp_b, float* __restrict__ hbuf) {
  __shared__ __align__(16) unsigned int a[16 * 132];
  int id = blockIdx.x;
  int s = id >> 7;
  int rem = id & 127;
  int b0 = (rem >> 1) * 16;
  int e0 = (rem & 1) * 128;
  int tid = threadIdx.x, lane = tid & 63, wave = tid >> 6;
  int row16 = lane & 15, quad = lane >> 4;
  f32x4 acc[2];
#pragma unroll
  for (int t = 0; t < 2; ++t)
#pragma unroll
    for (int cc = 0; cc < 4; ++cc) acc[t][cc] = 0.f;

  for (int kc = 0; kc < 6; ++kc) {
    __syncthreads();
    for (int j = tid; j < 512; j += 256) {
      int rw = j >> 5, ck = j & 31;
      bf16x8 v = *(const bf16x8*)(feats + ((size_t)s * B_ + b0 + rw) * K6_ + kc * 256 + ck * 8);
      *(bf16x8*)((unsigned short*)&a[rw * 132] + ck * 8) = v;
    }
    __syncthreads();
#pragma unroll
    for (int ks = 0; ks < 8; ++ks) {
      bf16x8 af = *(const bf16x8*)&a[row16 * 132 + ks * 16 + quad * 4];
#pragma unroll
      for (int t = 0; t < 2; ++t) {
        int e = e0 + wave * 32 + t * 16 + row16;
        bf16x8 bfr = *(const bf16x8*)(spw_bf + ((size_t)s * E_ + e) * K6_ + kc * 256 + ks * 32 + quad * 8);
        acc[t] = __builtin_amdgcn_mfma_f32_16x16x32_bf16(af, bfr, acc[t], 0, 0, 0);
      }
    }
  }
#pragma unroll
  for (int t = 0; t < 2; ++t) {
    int e = e0 + wave * 32 + t * 16 + row16;
    float bias = sp_b[s * 256 + e];
#pragma unroll
    for (int rg = 0; rg < 4; ++rg) {
      int rw = quad * 4 + rg;
      hbuf[((size_t)s * B_ + b0 + rw) * 256 + e] = acc[t][rg] + bias;
    }
  }
}

// ------- K3: per b: for each s LN+gelu, weighted sum, final LN -> out -------
__global__ __launch_bounds__(256) void k3_kernel(
    const float* __restrict__ hbuf, const float* __restrict__ wts,
    const float* __restrict__ ln_g, const float* __restrict__ ln_b,
    const float* __restrict__ on_g, const float* __restrict__ on_b,
    float* __restrict__ out) {
  __shared__ float rs[4], rq[4];
  int b = blockIdx.x, tid = threadIdx.x, lane = tid & 63, wave = tid >> 6;
  float o = 0.f;
#pragma unroll
  for (int s = 0; s < 3; ++s) {
    float h = hbuf[((size_t)s * B_ + b) * 256 + tid];
    float sum = h, sq = h * h;
#pragma unroll
    for (int off = 32; off >= 1; off >>= 1) {
      sum += __shfl_xor(sum, off, 64);
      sq += __shfl_xor(sq, off, 64);
    }
    if (lane == 0) { rs[wave] = sum; rq[wave] = sq; }
    __syncthreads();
    float ts = rs[0] + rs[1] + rs[2] + rs[3];
    float tq = rq[0] + rq[1] + rq[2] + rq[3];
    __syncthreads();
    float mu = ts * (1.f / 256.f);
    float var = tq * (1.f / 256.f) - mu * mu;
    float rstd = rsqrtf(var + 1e-5f);
    float v = (h - mu) * rstd * ln_g[s * 256 + tid] + ln_b[s * 256 + tid];
    o += wts[b * 4 + s] * gelu_exact(v);
  }
  float sum = o, sq = o * o;
#pragma unroll
  for (int off = 32; off >= 1; off >>= 1) {
    sum += __shfl_xor(sum, off, 64);
    sq += __shfl_xor(sq, off, 64);
  }
  if (lane == 0) { rs[wave] = sum; rq[wave] = sq; }
  __syncthreads();
  float ts = rs[0] + rs[1] + rs[2] + rs[3];
  float tq = rq[0] + rq[1] + rq[2] + rq[3];
  float mu = ts * (1.f / 256.f);
  float var = tq * (1.f / 256.f) - mu * mu;
  float rstd = rsqrtf(var + 1e-5f);
  out[(size_t)b * 256 + tid] = (o - mu) * rstd * on_g[tid] + on_b[tid];
}

extern "C" void kernel_launch(void* const* d_in, const int* in_sizes, int n_in,
                              void* d_out, int out_size, void* d_ws, size_t ws_size,
                              hipStream_t stream) {
  const float* e_emb   = (const float*)d_in[0];
  const float* nb_rel  = (const float*)d_in[1];
  const float* delta_t = (const float*)d_in[2];
  const float* r_emb   = (const float*)d_in[3];
  const unsigned char* hist_mask = (const unsigned char*)d_in[4]; // dtype auto-detected
  const float* rel_w   = (const float*)d_in[5];
  const float* lt1     = (const float*)d_in[6];
  const float* lt2     = (const float*)d_in[7];
  const float* shp     = (const float*)d_in[8];
  const float* lgm     = (const float*)d_in[9];
  const float* attn_w  = (const float*)d_in[10];
  const float* sp_w    = (const float*)d_in[11];
  const float* sp_b    = (const float*)d_in[12];
  const float* ln_g    = (const float*)d_in[13];
  const float* ln_b    = (const float*)d_in[14];
  const float* csq_w   = (const float*)d_in[15];
  const float* csq_b   = (const float*)d_in[16];
  const float* csl_w   = (const float*)d_in[17];
  const float* csl_b   = (const float*)d_in[18];
  const float* on_g    = (const float*)d_in[19];
  const float* on_b    = (const float*)d_in[20];
  float* out = (float*)d_out;

  char* ws = (char*)d_ws;
  unsigned short* rw_bf  = (unsigned short*)(ws + 0);         // 131072 B
  unsigned short* spw_bf = (unsigned short*)(ws + 131072);    // 2359296 B
  unsigned short* t_bf   = (unsigned short*)(ws + 2490368);   // 1572864 B
  float* wts    = (float*)(ws + 4063232);                     // 16 KB
  unsigned short* feats = (unsigned short*)(ws + 4079616);    // 9437184 B
  float* hbuf   = (float*)(ws + 13516800);                    // 3 MB (total ~16.7 MB)

  hipLaunchKernelGGL(k_cast, dim3(4864), dim3(256), 0, stream, rel_w, sp_w, rw_bf, spw_bf);
  hipLaunchKernelGGL(k_prep, dim3(256), dim3(256), 0, stream, r_emb, rel_w, csq_w, csq_b,
                     csl_w, csl_b, attn_w, t_bf, wts);
  hipLaunchKernelGGL(k1_main, dim3(1024), dim3(1024), 0, stream, nb_rel, delta_t, hist_mask,
                     e_emb, lt1, lt2, shp, lgm, rw_bf, t_bf, feats);
  hipLaunchKernelGGL(k2_kernel, dim3(384), dim3(256), 0, stream, feats, spw_bf, sp_b, hbuf);
  hipLaunchKernelGGL(k3_kernel, dim3(1024), dim3(256), 0, stream, hbuf, wts, ln_g, ln_b,
                     on_g, on_b, out);
}